// Round 1
// baseline (71.770 us; speedup 1.0000x reference)
//
#include <hip/hip_runtime.h>
#include <math.h>

// CapsuleLayer dynamic routing, fused single kernel.
// B=8, I=32, C=8, HW=256, O=16, h=16, NUM_ROUTING=3.
// Block = 4 consecutive pixels (same b), 256 threads = 4 waves.
//   wave w: owns i-slice [8w,8w+8) for votes/distances/softmax rows,
//           and pixel p=w for combine/squash/output.
//   lane l: owns m = 4l..4l+3  (o = l>>2, h = (l&3)*4+j)
// Votes (8192 floats/pixel) stay in registers: float4 v[8][4] = 128 VGPRs.

__device__ __forceinline__ float4 f4zero() { return make_float4(0.f, 0.f, 0.f, 0.f); }

__device__ __forceinline__ void fma4(float4& a, float s, const float4& q) {
    a.x = fmaf(s, q.x, a.x); a.y = fmaf(s, q.y, a.y);
    a.z = fmaf(s, q.z, a.z); a.w = fmaf(s, q.w, a.w);
}

__global__ __launch_bounds__(256, 2)
void caps_kernel(const float* __restrict__ x,
                 const float* __restrict__ wgt,
                 const float* __restrict__ bias,
                 float* __restrict__ out)
{
    __shared__ float s_route [4 * 512];   // [w][p][ii][o]
    __shared__ float s_logits[4 * 512];   // [w][p][ii][o]
    __shared__ float s_part  [16 * 256];  // [w*4+p][m]  cross-wave preact partials
    __shared__ float s_act   [4 * 256];   // [p][m]

    const int t   = threadIdx.x;
    const int w   = t >> 6;               // wave id
    const int l   = t & 63;               // lane id
    const int b   = blockIdx.x >> 6;      // batch
    const int hw0 = (blockIdx.x & 63) << 2; // first of 4 pixels

    const float4 bias4 = ((const float4*)bias)[l];   // bias[m4..m4+3]

    // ---------------- votes: v[ii][p] = sum_c x[b,i,c,hw0+p] * W[i,c,4l..4l+3]
    float4 v[8][4];
    {
        const float*  xb = x + (size_t)b * 65536 + hw0;
        const float4* w4 = (const float4*)wgt;
        #pragma unroll
        for (int ii = 0; ii < 8; ++ii) {
            const int i = __builtin_amdgcn_readfirstlane((w << 3) + ii); // force SGPR for x addressing
            #pragma unroll
            for (int p = 0; p < 4; ++p) v[ii][p] = f4zero();
            #pragma unroll
            for (int c = 0; c < 8; ++c) {
                const float4 wv = w4[i * 512 + c * 64 + l];              // coalesced dwordx4
                const float4 xv = *(const float4*)(xb + (i * 8 + c) * 256); // wave-uniform -> s_load
                fma4(v[ii][0], xv.x, wv);
                fma4(v[ii][1], xv.y, wv);
                fma4(v[ii][2], xv.z, wv);
                fma4(v[ii][3], xv.w, wv);
            }
        }
    }

    float4 actreg = f4zero();

    #pragma unroll
    for (int it = 0; it < 3; ++it) {
        float4 pre[4];
        if (it == 0) {
            // softmax of zero logits == 1/16 exactly: skip softmax + route LDS entirely
            #pragma unroll
            for (int p = 0; p < 4; ++p) {
                float4 s = v[0][p];
                #pragma unroll
                for (int ii = 1; ii < 8; ++ii) {
                    s.x += v[ii][p].x; s.y += v[ii][p].y;
                    s.z += v[ii][p].z; s.w += v[ii][p].w;
                }
                pre[p] = make_float4(s.x * 0.0625f, s.y * 0.0625f,
                                     s.z * 0.0625f, s.w * 0.0625f);
            }
        } else {
            // softmax over o: row r = l>>1 (p=r>>3, ii=r&7), half = l&1 handles 8 o's
            const int base = w * 512 + (l >> 1) * 16 + (l & 1) * 8;
            const float4 la = *(const float4*)&s_logits[base];
            const float4 lb = *(const float4*)&s_logits[base + 4];
            float mx = fmaxf(fmaxf(fmaxf(la.x, la.y), fmaxf(la.z, la.w)),
                             fmaxf(fmaxf(lb.x, lb.y), fmaxf(lb.z, lb.w)));
            mx = fmaxf(mx, __shfl_xor(mx, 1));
            const float e0 = __expf(la.x - mx), e1 = __expf(la.y - mx);
            const float e2 = __expf(la.z - mx), e3 = __expf(la.w - mx);
            const float e4 = __expf(lb.x - mx), e5 = __expf(lb.y - mx);
            const float e6 = __expf(lb.z - mx), e7 = __expf(lb.w - mx);
            float sum = ((e0 + e1) + (e2 + e3)) + ((e4 + e5) + (e6 + e7));
            sum += __shfl_xor(sum, 1);
            const float inv = 1.f / sum;
            *(float4*)&s_route[base]     = make_float4(e0 * inv, e1 * inv, e2 * inv, e3 * inv);
            *(float4*)&s_route[base + 4] = make_float4(e4 * inv, e5 * inv, e6 * inv, e7 * inv);
            __syncthreads();  // safety: route produced by other lanes of this wave

            #pragma unroll
            for (int p = 0; p < 4; ++p) pre[p] = f4zero();
            const int rb = w * 512 + (l >> 2);
            #pragma unroll
            for (int ii = 0; ii < 8; ++ii) {
                #pragma unroll
                for (int p = 0; p < 4; ++p) {
                    const float r = s_route[rb + p * 128 + ii * 16];  // broadcast read
                    fma4(pre[p], r, v[ii][p]);
                }
            }
        }

        // stage partial preacts (this wave's i-slice contribution, all 4 pixels)
        #pragma unroll
        for (int p = 0; p < 4; ++p)
            *(float4*)&s_part[(w * 4 + p) * 256 + 4 * l] = pre[p];
        __syncthreads();  // S1

        // combine across waves for pixel p=w, add bias, squash
        float4 acc = bias4;
        #pragma unroll
        for (int wp = 0; wp < 4; ++wp) {
            const float4 q = *(const float4*)&s_part[(wp * 4 + w) * 256 + 4 * l];
            acc.x += q.x; acc.y += q.y; acc.z += q.z; acc.w += q.w;
        }
        float sq = acc.x * acc.x + acc.y * acc.y + acc.z * acc.z + acc.w * acc.w;
        sq += __shfl_xor(sq, 1);
        sq += __shfl_xor(sq, 2);          // full sum over 16 h (4-lane group)
        const float f = sqrtf(sq) / (1.f + sq);   // s/||s|| * ||s||^2/(1+||s||^2)
        actreg = make_float4(acc.x * f, acc.y * f, acc.z * f, acc.w * f);

        if (it < 2) {
            *(float4*)&s_act[w * 256 + 4 * l] = actreg;   // broadcast act of pixel w
            __syncthreads();  // S2

            // distances[p][i][o] = sum_h votes * act ; accumulate into logits
            float dacc[8];
            #pragma unroll
            for (int ii = 0; ii < 8; ++ii) dacc[ii] = 0.f;
            #pragma unroll
            for (int p = 0; p < 4; ++p) {
                const float4 a = *(const float4*)&s_act[p * 256 + 4 * l];
                #pragma unroll
                for (int ii = 0; ii < 8; ++ii) {
                    float d = v[ii][p].x * a.x + v[ii][p].y * a.y
                            + v[ii][p].z * a.z + v[ii][p].w * a.w;
                    d += __shfl_xor(d, 1);
                    d += __shfl_xor(d, 2);            // full dot over 16 h
                    dacc[ii] = ((l & 3) == p) ? d : dacc[ii]; // lane keeps pixel l&3
                }
            }
            const int lb2 = w * 512 + (l & 3) * 128 + (l >> 2); // [w][p=l&3][ii][o=l>>2]
            if (it == 0) {
                #pragma unroll
                for (int ii = 0; ii < 8; ++ii) s_logits[lb2 + ii * 16] = dacc[ii];
            } else {
                #pragma unroll
                for (int ii = 0; ii < 8; ++ii) s_logits[lb2 + ii * 16] += dacc[ii];
            }
            __syncthreads();  // S3
        }
    }

    // ---------------- output: out[b, m, hw] ; transpose via s_act for float4 stores
    *(float4*)&s_act[w * 256 + 4 * l] = actreg;
    __syncthreads();
    float4 o4;
    o4.x = s_act[t];
    o4.y = s_act[256 + t];
    o4.z = s_act[512 + t];
    o4.w = s_act[768 + t];
    *(float4*)(out + (size_t)b * 65536 + (size_t)t * 256 + hw0) = o4;
}

extern "C" void kernel_launch(void* const* d_in, const int* in_sizes, int n_in,
                              void* d_out, int out_size, void* d_ws, size_t ws_size,
                              hipStream_t stream) {
    const float* x    = (const float*)d_in[0];   // (8,32,8,16,16)
    const float* wgt  = (const float*)d_in[1];   // (32,8,256)
    const float* bias = (const float*)d_in[2];   // (16,16,1,1)
    float* out = (float*)d_out;                  // (8,16,16,16,16)
    caps_kernel<<<dim3(512), dim3(256), 0, stream>>>(x, wgt, bias, out);
}